// Round 1
// baseline (5796.770 us; speedup 1.0000x reference)
//
#include <hip/hip_runtime.h>
#include <math.h>

#define B_   2
#define N_   20480
#define C_   256
#define M_   2048
#define ND_  16384
#define NS_  512
#define NV_  800
#define NA_  12
#define NDp_ 7
#define NAD_ 84  // 12*7

// output offsets (floats)
#define OFF_XYZ  0LL
#define OFF_FEAT 12288LL
#define OFF_AFF  1060864LL
#define OFF_VS   1093632LL
#define OFF_GS   1912832LL
#define TOTAL_OUT 70725632LL

// ---------------------------------------------------------------------------
// Fibonacci-sphere views, computed in double to bit-match numpy f64 -> f32
// ---------------------------------------------------------------------------
__global__ void views_kernel(float* __restrict__ views) {
    int i = blockIdx.x * blockDim.x + threadIdx.x;
    if (i >= NV_) return;
    const double phi = (sqrt(5.0) - 1.0) * 0.5;
    double zi = (2.0 * (double)i + 1.0) / (double)NV_ - 1.0;
    double r2 = 1.0 - zi * zi;
    if (r2 < 0.0) r2 = 0.0;
    double r = sqrt(r2);
    // numpy: 2.0 * np.pi * i * phi  ==  ((2.0*pi) * i) * phi
    double ang = ((2.0 * 3.14159265358979311600) * (double)i) * phi;
    views[i * 3 + 0] = (float)(r * cos(ang));
    views[i * 3 + 1] = (float)(r * sin(ang));
    views[i * 3 + 2] = (float)zi;
}

// ---------------------------------------------------------------------------
// Masked furthest-point sampling. One block per batch. All points + dists in
// registers. IEEE no-FMA arithmetic to bit-match numpy.
// ---------------------------------------------------------------------------
#define FPS_T 512
#define FPS_P (N_ / FPS_T)  // 40 points per thread

__global__ __launch_bounds__(FPS_T) void fps_kernel(
    const float* __restrict__ xyz, const float* __restrict__ gs,
    int* __restrict__ fps_idx)
{
    const int b = blockIdx.x;
    const float* __restrict__ X = xyz + (size_t)b * N_ * 3;
    const float* __restrict__ G = gs + (size_t)b * N_;
    const int t = threadIdx.x;
    const int lane = t & 63;
    const int wid = t >> 6;

    float px[FPS_P], py[FPS_P], pz[FPS_P], dd[FPS_P];
    int firstvalid = 0x7fffffff;
#pragma unroll
    for (int i = 0; i < FPS_P; i++) {
        int p = t + FPS_T * i;
        px[i] = X[3 * p];
        py[i] = X[3 * p + 1];
        pz[i] = X[3 * p + 2];
        bool m = G[p] > 0.001f;
        dd[i] = m ? 1e10f : -1.0f;
        if (m && p < firstvalid) firstvalid = p;
    }

    __shared__ float s_v[FPS_T / 64];
    __shared__ int   s_i[FPS_T / 64];
    __shared__ int   s_win;

    // block-wide min(firstvalid) == argmax(mask)
    int fv = firstvalid;
#pragma unroll
    for (int o = 32; o > 0; o >>= 1) {
        int ov = __shfl_xor(fv, o);
        fv = min(fv, ov);
    }
    if (lane == 0) s_i[wid] = fv;
    __syncthreads();
    if (t == 0) {
        int m = s_i[0];
        for (int w = 1; w < FPS_T / 64; w++) m = min(m, s_i[w]);
        s_win = m;
        fps_idx[b * M_ + 0] = m;
    }
    __syncthreads();
    int last = s_win;

    for (int it = 1; it < M_; it++) {
        float xl = X[3 * last], yl = X[3 * last + 1], zl = X[3 * last + 2];
        float bv = -2.0f;
        int bi = 0;
#pragma unroll
        for (int i = 0; i < FPS_P; i++) {
            float dx = __fsub_rn(px[i], xl);
            float dy = __fsub_rn(py[i], yl);
            float dz = __fsub_rn(pz[i], zl);
            // ((dx*dx + dy*dy) + dz*dz), no FMA — matches numpy bit-exactly
            float d = __fadd_rn(__fadd_rn(__fmul_rn(dx, dx), __fmul_rn(dy, dy)),
                                __fmul_rn(dz, dz));
            float nd = fminf(dd[i], d);
            dd[i] = nd;
            if (nd > bv) { bv = nd; bi = t + FPS_T * i; }  // ascending idx, strict >
        }
        // wave argmax (max value, lowest index on ties)
#pragma unroll
        for (int o = 32; o > 0; o >>= 1) {
            float ov = __shfl_xor(bv, o);
            int   oi = __shfl_xor(bi, o);
            if (ov > bv || (ov == bv && oi < bi)) { bv = ov; bi = oi; }
        }
        if (lane == 0) { s_v[wid] = bv; s_i[wid] = bi; }
        __syncthreads();
        if (t == 0) {
            float v = s_v[0];
            int idx = s_i[0];
            for (int w = 1; w < FPS_T / 64; w++) {
                float ov = s_v[w]; int oi = s_i[w];
                if (ov > v || (ov == v && oi < idx)) { v = ov; idx = oi; }
            }
            s_win = idx;
            fps_idx[b * M_ + it] = idx;
        }
        __syncthreads();
        last = s_win;
    }
}

// ---------------------------------------------------------------------------
// Gather xyz + features at fps indices. One block per (b,m).
// ---------------------------------------------------------------------------
__global__ __launch_bounds__(256) void gather_kernel(
    const float* __restrict__ xyz, const float* __restrict__ feat,
    const int* __restrict__ fps_idx, float* __restrict__ out)
{
    int bm = blockIdx.x;               // 0 .. B*M-1
    int b = bm / M_;
    int idx = fps_idx[bm];
    const float* src = feat + ((size_t)b * N_ + idx) * C_;
    float* dst = out + OFF_FEAT + (size_t)bm * C_;
    dst[threadIdx.x] = src[threadIdx.x];
    if (threadIdx.x < 3)
        out[OFF_XYZ + (size_t)bm * 3 + threadIdx.x] =
            xyz[((size_t)b * N_ + idx) * 3 + threadIdx.x];
}

// ---------------------------------------------------------------------------
// Affordance: 2-NN of dense points among valid sparse points, mean of scores.
// ---------------------------------------------------------------------------
__global__ __launch_bounds__(256) void aff_kernel(
    const float* __restrict__ dense, const float* __restrict__ sparse,
    const float* __restrict__ scores, float* __restrict__ out)
{
    __shared__ float sx[NS_], sy[NS_], sz[NS_], ss2[NS_], ssc[NS_];
    __shared__ unsigned char sval[NS_];
    const int b = blockIdx.y;
    const float* SP = sparse + (size_t)b * NS_ * 3;
    for (int j = threadIdx.x; j < NS_; j += 256) {
        float x = SP[3 * j], y = SP[3 * j + 1], z = SP[3 * j + 2];
        sx[j] = x; sy[j] = y; sz[j] = z;
        ss2[j] = __fadd_rn(__fadd_rn(__fmul_rn(x, x), __fmul_rn(y, y)),
                           __fmul_rn(z, z));
        sval[j] = (x != 0.0f) || (y != 0.0f) || (z != 0.0f);
        ssc[j] = scores[(size_t)b * NS_ + j];
    }
    __syncthreads();
    int n = blockIdx.x * 256 + threadIdx.x;
    const float* D = dense + ((size_t)b * ND_ + n) * 3;
    float x = D[0], y = D[1], z = D[2];
    float ds2 = __fadd_rn(__fadd_rn(__fmul_rn(x, x), __fmul_rn(y, y)),
                          __fmul_rn(z, z));
    float b1 = 1e30f, b2 = 1e30f;
    int i1 = 0, i2 = 0;
    for (int j = 0; j < NS_; j++) {
        float dot = __fadd_rn(__fadd_rn(__fmul_rn(x, sx[j]), __fmul_rn(y, sy[j])),
                              __fmul_rn(z, sz[j]));
        float d2 = __fsub_rn(__fadd_rn(ds2, ss2[j]), __fmul_rn(2.0f, dot));
        d2 = sval[j] ? d2 : 1e10f;
        if (d2 < b1)      { b2 = b1; i2 = i1; b1 = d2; i1 = j; }
        else if (d2 < b2) { b2 = d2; i2 = j; }
    }
    out[OFF_AFF + (size_t)b * ND_ + n] = (ssc[i1] + ssc[i2]) * 0.5f;
}

// ---------------------------------------------------------------------------
// View argmax (1 wave per (b,n)) + scatter with last-k-wins dedup.
// ---------------------------------------------------------------------------
__global__ __launch_bounds__(256) void scatter_kernel(
    const float* __restrict__ sparse, const float* __restrict__ appr,
    const float* __restrict__ nvs, const float* __restrict__ ngs,
    const float* __restrict__ views, float* __restrict__ out)
{
    __shared__ float vx[NV_], vy[NV_], vz[NV_];
    const int t = threadIdx.x;
    for (int v = t; v < NV_; v += 256) {
        vx[v] = views[3 * v];
        vy[v] = views[3 * v + 1];
        vz[v] = views[3 * v + 2];
    }
    __syncthreads();
    const int wid = t >> 6, lane = t & 63;
    const int gw = blockIdx.x * 4 + wid;  // 0 .. B*NS-1
    const int b = gw / NS_, n = gw % NS_;
    const float* SP = sparse + ((size_t)b * NS_ + n) * 3;
    float vm = ((SP[0] != 0.0f) || (SP[1] != 0.0f) || (SP[2] != 0.0f)) ? 1.0f : 0.0f;

    int vind[3];
#pragma unroll
    for (int k = 0; k < 3; k++) {
        const float* A = appr + (((size_t)b * NS_ + n) * 3 + k) * 3;
        float ax = A[0], ay = A[1], az = A[2];
        float bv = -1e30f;
        int bi = 0x7fffffff;
        for (int v = lane; v < NV_; v += 64) {
            float d = __fadd_rn(__fadd_rn(__fmul_rn(ax, vx[v]), __fmul_rn(ay, vy[v])),
                                __fmul_rn(az, vz[v]));
            if (d > bv) { bv = d; bi = v; }  // ascending v, strict >
        }
#pragma unroll
        for (int o = 32; o > 0; o >>= 1) {
            float ov = __shfl_xor(bv, o);
            int   oi = __shfl_xor(bi, o);
            if (ov > bv || (ov == bv && oi < bi)) { bv = ov; bi = oi; }
        }
        vind[k] = bi;
    }
    // last k wins on duplicate view index (numpy fancy-assignment semantics)
    bool wk0 = (vind[0] != vind[1]) && (vind[0] != vind[2]);
    bool wk1 = (vind[1] != vind[2]);
    bool wk[3] = { wk0, wk1, true };

    size_t row = (size_t)b * NS_ + n;
    if (lane < 3 && wk[lane]) {
        out[OFF_VS + row * NV_ + vind[lane]] = nvs[row * 3 + lane] * vm;
    }
#pragma unroll
    for (int k = 0; k < 3; k++) {
        if (!wk[k]) continue;
        const float* S = ngs + (row * 3 + k) * NAD_;
        float* Dst = out + OFF_GS + (row * NV_ + (size_t)vind[k]) * NAD_;
        for (int j = lane; j < NAD_; j += 64) Dst[j] = S[j] * vm;
    }
}

// ---------------------------------------------------------------------------
extern "C" void kernel_launch(void* const* d_in, const int* in_sizes, int n_in,
                              void* d_out, int out_size, void* d_ws, size_t ws_size,
                              hipStream_t stream) {
    const float* seed_xyz      = (const float*)d_in[0];
    const float* seed_features = (const float*)d_in[1];
    const float* graspness     = (const float*)d_in[2];
    const float* dense_points  = (const float*)d_in[3];
    const float* sparse_points = (const float*)d_in[4];
    const float* norm_scores   = (const float*)d_in[5];
    const float* approach      = (const float*)d_in[6];
    const float* nvs           = (const float*)d_in[7];
    const float* ngs           = (const float*)d_in[8];
    float* out = (float*)d_out;

    int*   fps_idx = (int*)d_ws;
    float* views   = (float*)((char*)d_ws + 16384);

    // zero view_scores + grasp_scores region (rest is fully overwritten)
    hipMemsetAsync((char*)d_out + (size_t)OFF_VS * 4, 0,
                   (size_t)(TOTAL_OUT - OFF_VS) * 4, stream);

    views_kernel<<<dim3(4), dim3(256), 0, stream>>>(views);
    fps_kernel<<<dim3(B_), dim3(FPS_T), 0, stream>>>(seed_xyz, graspness, fps_idx);
    gather_kernel<<<dim3(B_ * M_), dim3(256), 0, stream>>>(seed_xyz, seed_features,
                                                           fps_idx, out);
    aff_kernel<<<dim3(ND_ / 256, B_), dim3(256), 0, stream>>>(dense_points,
                                                              sparse_points,
                                                              norm_scores, out);
    scatter_kernel<<<dim3((B_ * NS_) / 4), dim3(256), 0, stream>>>(
        sparse_points, approach, nvs, ngs, views, out);
}

// Round 2
// 5678.067 us; speedup vs baseline: 1.0209x; 1.0209x over previous
//
#include <hip/hip_runtime.h>
#include <math.h>

#define B_   2
#define N_   20480
#define C_   256
#define M_   2048
#define ND_  16384
#define NS_  512
#define NV_  800
#define NA_  12
#define NDp_ 7
#define NAD_ 84  // 12*7

// output offsets (floats)
#define OFF_XYZ  0LL
#define OFF_FEAT 12288LL
#define OFF_AFF  1060864LL
#define OFF_VS   1093632LL
#define OFF_GS   1912832LL
#define TOTAL_OUT 70725632LL

// ---------------------------------------------------------------------------
// Fibonacci-sphere views, computed in double to bit-match numpy f64 -> f32
// ---------------------------------------------------------------------------
__global__ void views_kernel(float* __restrict__ views) {
    int i = blockIdx.x * blockDim.x + threadIdx.x;
    if (i >= NV_) return;
    const double phi = (sqrt(5.0) - 1.0) * 0.5;
    double zi = (2.0 * (double)i + 1.0) / (double)NV_ - 1.0;
    double r2 = 1.0 - zi * zi;
    if (r2 < 0.0) r2 = 0.0;
    double r = sqrt(r2);
    double ang = ((2.0 * 3.14159265358979311600) * (double)i) * phi;
    views[i * 3 + 0] = (float)(r * cos(ang));
    views[i * 3 + 1] = (float)(r * sin(ang));
    views[i * 3 + 2] = (float)zi;
}

// ---------------------------------------------------------------------------
// Masked furthest-point sampling. One block per batch. All points + dists in
// registers (launch_bounds(512,2) -> 256 VGPR budget, no spills).
// One barrier per iteration; double-buffered LDS reduction entries; winner
// coords fetched via uniform scalar load.
// ---------------------------------------------------------------------------
#define FPS_T 512
#define FPS_P (N_ / FPS_T)  // 40 points per thread
#define FPS_W (FPS_T / 64)  // 8 waves

__global__ __launch_bounds__(FPS_T, 2) void fps_kernel(
    const float* __restrict__ xyz, const float* __restrict__ gs,
    int* __restrict__ fps_idx)
{
    const int b = blockIdx.x;
    const float* __restrict__ X = xyz + (size_t)b * N_ * 3;
    const float* __restrict__ G = gs + (size_t)b * N_;
    const int t = threadIdx.x;
    const int lane = t & 63;
    const int wid = t >> 6;

    float px[FPS_P], py[FPS_P], pz[FPS_P], dd[FPS_P];
    int firstvalid = 0x7fffffff;
#pragma unroll
    for (int i = 0; i < FPS_P; i++) {
        int p = t + FPS_T * i;
        px[i] = X[3 * p];
        py[i] = X[3 * p + 1];
        pz[i] = X[3 * p + 2];
        bool m = G[p] > 0.001f;
        dd[i] = m ? 1e10f : -1.0f;
        if (m && p < firstvalid) firstvalid = p;
    }

    __shared__ float2 s_e[2][FPS_W];   // {value, bitcast index}, parity-buffered
    __shared__ int    s_first[FPS_W];

    // ---- first index: block-wide min(firstvalid) == argmax(mask) ----
    int fv = firstvalid;
#pragma unroll
    for (int o = 32; o > 0; o >>= 1) fv = min(fv, __shfl_xor(fv, o));
    if (lane == 0) s_first[wid] = fv;
    __syncthreads();
    int start = s_first[0];
#pragma unroll
    for (int w = 1; w < FPS_W; w++) start = min(start, s_first[w]);
    if (t == 0) fps_idx[b * M_ + 0] = start;

    int u = __builtin_amdgcn_readfirstlane(start);
    float xl = X[3 * u], yl = X[3 * u + 1], zl = X[3 * u + 2];

    for (int it = 1; it < M_; it++) {
        float bv = -2.0f;
        int bi = 0;
#pragma unroll
        for (int i = 0; i < FPS_P; i++) {
            float dx = __fsub_rn(px[i], xl);
            float dy = __fsub_rn(py[i], yl);
            float dz = __fsub_rn(pz[i], zl);
            // ((dx*dx + dy*dy) + dz*dz), no FMA — matches numpy bit-exactly
            float d = __fadd_rn(__fadd_rn(__fmul_rn(dx, dx), __fmul_rn(dy, dy)),
                                __fmul_rn(dz, dz));
            float nd = fminf(dd[i], d);
            dd[i] = nd;
            if (nd > bv) { bv = nd; bi = t + FPS_T * i; }  // ascending idx, strict >
        }
        // wave argmax (max value, lowest index on ties)
#pragma unroll
        for (int o = 32; o > 0; o >>= 1) {
            float ov = __shfl_xor(bv, o);
            int   oi = __shfl_xor(bi, o);
            if (ov > bv || (ov == bv && oi < bi)) { bv = ov; bi = oi; }
        }
        const int par = it & 1;
        if (lane == 0) s_e[par][wid] = make_float2(bv, __int_as_float(bi));
        __syncthreads();
        // every thread redundantly reduces the 8 wave entries (no 2nd barrier)
        float2 e0 = s_e[par][0];
        float v = e0.x;
        int idx = __float_as_int(e0.y);
#pragma unroll
        for (int w = 1; w < FPS_W; w++) {
            float2 e = s_e[par][w];
            float ov = e.x; int oi = __float_as_int(e.y);
            if (ov > v || (ov == v && oi < idx)) { v = ov; idx = oi; }
        }
        if (t == 0) fps_idx[b * M_ + it] = idx;
        u = __builtin_amdgcn_readfirstlane(idx);
        xl = X[3 * u]; yl = X[3 * u + 1]; zl = X[3 * u + 2];
    }
}

// ---------------------------------------------------------------------------
// Gather xyz + features at fps indices. One block per (b,m).
// ---------------------------------------------------------------------------
__global__ __launch_bounds__(256) void gather_kernel(
    const float* __restrict__ xyz, const float* __restrict__ feat,
    const int* __restrict__ fps_idx, float* __restrict__ out)
{
    int bm = blockIdx.x;               // 0 .. B*M-1
    int b = bm / M_;
    int idx = fps_idx[bm];
    const float* src = feat + ((size_t)b * N_ + idx) * C_;
    float* dst = out + OFF_FEAT + (size_t)bm * C_;
    dst[threadIdx.x] = src[threadIdx.x];
    if (threadIdx.x < 3)
        out[OFF_XYZ + (size_t)bm * 3 + threadIdx.x] =
            xyz[((size_t)b * N_ + idx) * 3 + threadIdx.x];
}

// ---------------------------------------------------------------------------
// Affordance: 2-NN of dense points among valid sparse points, mean of scores.
// ---------------------------------------------------------------------------
__global__ __launch_bounds__(256) void aff_kernel(
    const float* __restrict__ dense, const float* __restrict__ sparse,
    const float* __restrict__ scores, float* __restrict__ out)
{
    __shared__ float sx[NS_], sy[NS_], sz[NS_], ss2[NS_], ssc[NS_];
    __shared__ unsigned char sval[NS_];
    const int b = blockIdx.y;
    const float* SP = sparse + (size_t)b * NS_ * 3;
    for (int j = threadIdx.x; j < NS_; j += 256) {
        float x = SP[3 * j], y = SP[3 * j + 1], z = SP[3 * j + 2];
        sx[j] = x; sy[j] = y; sz[j] = z;
        ss2[j] = __fadd_rn(__fadd_rn(__fmul_rn(x, x), __fmul_rn(y, y)),
                           __fmul_rn(z, z));
        sval[j] = (x != 0.0f) || (y != 0.0f) || (z != 0.0f);
        ssc[j] = scores[(size_t)b * NS_ + j];
    }
    __syncthreads();
    int n = blockIdx.x * 256 + threadIdx.x;
    const float* D = dense + ((size_t)b * ND_ + n) * 3;
    float x = D[0], y = D[1], z = D[2];
    float ds2 = __fadd_rn(__fadd_rn(__fmul_rn(x, x), __fmul_rn(y, y)),
                          __fmul_rn(z, z));
    float b1 = 1e30f, b2 = 1e30f;
    int i1 = 0, i2 = 0;
    for (int j = 0; j < NS_; j++) {
        float dot = __fadd_rn(__fadd_rn(__fmul_rn(x, sx[j]), __fmul_rn(y, sy[j])),
                              __fmul_rn(z, sz[j]));
        float d2 = __fsub_rn(__fadd_rn(ds2, ss2[j]), __fmul_rn(2.0f, dot));
        d2 = sval[j] ? d2 : 1e10f;
        if (d2 < b1)      { b2 = b1; i2 = i1; b1 = d2; i1 = j; }
        else if (d2 < b2) { b2 = d2; i2 = j; }
    }
    out[OFF_AFF + (size_t)b * ND_ + n] = (ssc[i1] + ssc[i2]) * 0.5f;
}

// ---------------------------------------------------------------------------
// View argmax (1 wave per (b,n)) + scatter with last-k-wins dedup.
// ---------------------------------------------------------------------------
__global__ __launch_bounds__(256) void scatter_kernel(
    const float* __restrict__ sparse, const float* __restrict__ appr,
    const float* __restrict__ nvs, const float* __restrict__ ngs,
    const float* __restrict__ views, float* __restrict__ out)
{
    __shared__ float vx[NV_], vy[NV_], vz[NV_];
    const int t = threadIdx.x;
    for (int v = t; v < NV_; v += 256) {
        vx[v] = views[3 * v];
        vy[v] = views[3 * v + 1];
        vz[v] = views[3 * v + 2];
    }
    __syncthreads();
    const int wid = t >> 6, lane = t & 63;
    const int gw = blockIdx.x * 4 + wid;  // 0 .. B*NS-1
    const int b = gw / NS_, n = gw % NS_;
    const float* SP = sparse + ((size_t)b * NS_ + n) * 3;
    float vm = ((SP[0] != 0.0f) || (SP[1] != 0.0f) || (SP[2] != 0.0f)) ? 1.0f : 0.0f;

    int vind[3];
#pragma unroll
    for (int k = 0; k < 3; k++) {
        const float* A = appr + (((size_t)b * NS_ + n) * 3 + k) * 3;
        float ax = A[0], ay = A[1], az = A[2];
        float bv = -1e30f;
        int bi = 0x7fffffff;
        for (int v = lane; v < NV_; v += 64) {
            float d = __fadd_rn(__fadd_rn(__fmul_rn(ax, vx[v]), __fmul_rn(ay, vy[v])),
                                __fmul_rn(az, vz[v]));
            if (d > bv) { bv = d; bi = v; }  // ascending v, strict >
        }
#pragma unroll
        for (int o = 32; o > 0; o >>= 1) {
            float ov = __shfl_xor(bv, o);
            int   oi = __shfl_xor(bi, o);
            if (ov > bv || (ov == bv && oi < bi)) { bv = ov; bi = oi; }
        }
        vind[k] = bi;
    }
    // last k wins on duplicate view index (numpy fancy-assignment semantics)
    bool wk0 = (vind[0] != vind[1]) && (vind[0] != vind[2]);
    bool wk1 = (vind[1] != vind[2]);
    bool wk[3] = { wk0, wk1, true };

    size_t row = (size_t)b * NS_ + n;
    if (lane < 3 && wk[lane]) {
        out[OFF_VS + row * NV_ + vind[lane]] = nvs[row * 3 + lane] * vm;
    }
#pragma unroll
    for (int k = 0; k < 3; k++) {
        if (!wk[k]) continue;
        const float* S = ngs + (row * 3 + k) * NAD_;
        float* Dst = out + OFF_GS + (row * NV_ + (size_t)vind[k]) * NAD_;
        for (int j = lane; j < NAD_; j += 64) Dst[j] = S[j] * vm;
    }
}

// ---------------------------------------------------------------------------
extern "C" void kernel_launch(void* const* d_in, const int* in_sizes, int n_in,
                              void* d_out, int out_size, void* d_ws, size_t ws_size,
                              hipStream_t stream) {
    const float* seed_xyz      = (const float*)d_in[0];
    const float* seed_features = (const float*)d_in[1];
    const float* graspness     = (const float*)d_in[2];
    const float* dense_points  = (const float*)d_in[3];
    const float* sparse_points = (const float*)d_in[4];
    const float* norm_scores   = (const float*)d_in[5];
    const float* approach      = (const float*)d_in[6];
    const float* nvs           = (const float*)d_in[7];
    const float* ngs           = (const float*)d_in[8];
    float* out = (float*)d_out;

    int*   fps_idx = (int*)d_ws;
    float* views   = (float*)((char*)d_ws + 16384);

    // zero view_scores + grasp_scores region (rest is fully overwritten)
    hipMemsetAsync((char*)d_out + (size_t)OFF_VS * 4, 0,
                   (size_t)(TOTAL_OUT - OFF_VS) * 4, stream);

    views_kernel<<<dim3(4), dim3(256), 0, stream>>>(views);
    fps_kernel<<<dim3(B_), dim3(FPS_T), 0, stream>>>(seed_xyz, graspness, fps_idx);
    gather_kernel<<<dim3(B_ * M_), dim3(256), 0, stream>>>(seed_xyz, seed_features,
                                                           fps_idx, out);
    aff_kernel<<<dim3(ND_ / 256, B_), dim3(256), 0, stream>>>(dense_points,
                                                              sparse_points,
                                                              norm_scores, out);
    scatter_kernel<<<dim3((B_ * NS_) / 4), dim3(256), 0, stream>>>(
        sparse_points, approach, nvs, ngs, views, out);
}